// Round 2
// baseline (8339.274 us; speedup 1.0000x reference)
//
#include <hip/hip_runtime.h>

// SimpleLSTM: B=128, T=8192, H=96 (4H=384 gates). One block per batch.
// 768 threads: 2 threads per gate row; thread (j, half) holds w_hh[j, half*48..+48)
// in 12 float4 registers (48 VGPRs) so the recurrent matvec runs from the RF,
// not from L1/L2 re-fetches (R1 failure mode: VGPR=64, weights re-read every
// step -> 2400 cyc/step cache-BW-bound).
// Per step (2 barriers):
//   phase 1: all 768 threads dot48(h, w) -> part_s[tid]
//   bar A
//   phase 2: tid<96 sum 8 partials, 4 activations, cell update,
//            write h into double-buffered h_s, y-reduction via shuffles
//   bar B

#define T_LEN 8192
#define H_DIM 96
#define G_DIM 384
#define NTHR  768

__device__ __forceinline__ float fast_sigmoid(float v) {
    return 1.0f / (1.0f + __expf(-v));
}
__device__ __forceinline__ float fast_tanh(float v) {
    // 1 - 2/(e^{2v}+1); stable at +-inf
    return 1.0f - 2.0f / (__expf(2.0f * v) + 1.0f);
}

__global__ __launch_bounds__(NTHR, 3) void lstm_seq_kernel(
    const float* __restrict__ x,      // [B, T, 1]
    const float* __restrict__ w_ih,   // [4H, 1]
    const float* __restrict__ w_hh,   // [4H, H]
    const float* __restrict__ b_ih,   // [4H]
    const float* __restrict__ b_hh,   // [4H]
    const float* __restrict__ w_out,  // [1, H]
    const float* __restrict__ b_out,  // [1]
    float* __restrict__ y)            // [B, T, 1]
{
    const int b    = blockIdx.x;
    const int tid  = threadIdx.x;
    const int half = (tid >= G_DIM) ? 1 : 0;   // wave-uniform (384 = 6-wave boundary)
    const int j    = tid - half * G_DIM;       // gate row 0..383

    __shared__ float h_s[2][H_DIM];   // double-buffered hidden state
    __shared__ float part_s[NTHR];    // raw dot partials (two halves)
    __shared__ float red_s[2];

    // 12 float4 = 48 weights per thread, from w_hh[j, half*48 ..)
    float4 wv[12];
    {
        const float4* wrow =
            reinterpret_cast<const float4*>(w_hh + j * H_DIM + half * 48);
        #pragma unroll
        for (int q = 0; q < 12; ++q) wv[q] = wrow[q];
    }

    // Cell-update params, only live on tid<96
    float bias4[4] = {0.f, 0.f, 0.f, 0.f};
    float wih4[4]  = {0.f, 0.f, 0.f, 0.f};
    float wout_j = 0.f;
    float c = 0.f;
    if (tid < H_DIM) {
        #pragma unroll
        for (int g = 0; g < 4; ++g) {
            bias4[g] = b_ih[g * H_DIM + tid] + b_hh[g * H_DIM + tid];
            wih4[g]  = w_ih[g * H_DIM + tid];
        }
        wout_j = w_out[tid];
        h_s[0][tid] = 0.f;
    }
    const float bout = b_out[0];
    __syncthreads();

    const float* xrow = x + (size_t)b * T_LEN;
    float*       yrow = y + (size_t)b * T_LEN;

    float x_next = 0.f;
    if (tid < H_DIM) x_next = xrow[0];

    for (int t = 0; t < T_LEN; ++t) {
        const float x_cur = x_next;
        if (tid < H_DIM && t + 1 < T_LEN) x_next = xrow[t + 1];

        const int p = t & 1;
        // 48-term dot: 12 broadcast ds_read_b128 + 48 FMAs in 4 chains
        const float4* h4 =
            reinterpret_cast<const float4*>(&h_s[p][half * 48]);
        float a0 = 0.f, a1 = 0.f, a2 = 0.f, a3 = 0.f;
        #pragma unroll
        for (int q = 0; q < 12; ++q) {
            const float4 hv = h4[q];
            a0 = fmaf(hv.x, wv[q].x, a0);
            a1 = fmaf(hv.y, wv[q].y, a1);
            a2 = fmaf(hv.z, wv[q].z, a2);
            a3 = fmaf(hv.w, wv[q].w, a3);
        }
        part_s[tid] = (a0 + a1) + (a2 + a3);
        __syncthreads();  // bar A: partials ready; everyone done reading h_s[p]

        float partial = 0.f;
        if (tid < 128) {
            if (tid < H_DIM) {
                const float s0 = part_s[tid]              + part_s[G_DIM + tid]
                               + bias4[0] + x_cur * wih4[0];
                const float s1 = part_s[H_DIM + tid]      + part_s[G_DIM + H_DIM + tid]
                               + bias4[1] + x_cur * wih4[1];
                const float s2 = part_s[2 * H_DIM + tid]  + part_s[G_DIM + 2 * H_DIM + tid]
                               + bias4[2] + x_cur * wih4[2];
                const float s3 = part_s[3 * H_DIM + tid]  + part_s[G_DIM + 3 * H_DIM + tid]
                               + bias4[3] + x_cur * wih4[3];
                const float ig = fast_sigmoid(s0);
                const float fg = fast_sigmoid(s1);
                const float gg = fast_tanh(s2);
                const float og = fast_sigmoid(s3);
                c = fg * c + ig * gg;
                const float h = og * fast_tanh(c);
                h_s[p ^ 1][tid] = h;
                partial = h * wout_j;
            }
            // y_t reduction over waves 0,1 (tid 96..127 contribute 0)
            #pragma unroll
            for (int off = 32; off > 0; off >>= 1)
                partial += __shfl_down(partial, off, 64);
            if ((tid & 63) == 0) red_s[tid >> 6] = partial;
        }
        __syncthreads();  // bar B: h_s[p^1] + red_s ready

        if (tid == 0) yrow[t] = red_s[0] + red_s[1] + bout;  // overlaps next dot
    }
}

extern "C" void kernel_launch(void* const* d_in, const int* in_sizes, int n_in,
                              void* d_out, int out_size, void* d_ws, size_t ws_size,
                              hipStream_t stream) {
    const float* x     = (const float*)d_in[0];
    const float* w_ih  = (const float*)d_in[1];
    const float* w_hh  = (const float*)d_in[2];
    const float* b_ih  = (const float*)d_in[3];
    const float* b_hh  = (const float*)d_in[4];
    const float* w_out = (const float*)d_in[5];
    const float* b_out = (const float*)d_in[6];
    float* y = (float*)d_out;

    const int B = 128;
    lstm_seq_kernel<<<dim3(B), dim3(NTHR), 0, stream>>>(
        x, w_ih, w_hh, b_ih, b_hh, w_out, b_out, y);
}

// Round 3
// 7547.539 us; speedup vs baseline: 1.1049x; 1.1049x over previous
//
#include <hip/hip_runtime.h>

// SimpleLSTM: B=128, T=8192, H=96 (4H=384 gates). One block per batch.
// 768 threads: thread (j, half) owns w_hh[j, half*48 .. half*48+48) -- 48
// floats = 24 VGPR pairs, PINNED via an empty inline-asm value barrier
// (R1/R2 failure: compiler remats the weight loads inside the t-loop,
// VGPR_Count=44/64, step becomes L2-BW-bound at ~2400 cyc).
// Dot product uses v_pk_fma_f32 (packed 2xfp32) to halve VALU issue.
// Per step (2 barriers):
//   phase 1: all 768 threads dot48(h, w) -> part_s[tid]
//   bar A
//   phase 2: tid<96: sum partials, 4 activations, cell update, write h
//            (double-buffered), y-reduction via shuffles
//   bar B

#define T_LEN 8192
#define H_DIM 96
#define G_DIM 384
#define NTHR  768

typedef float f2 __attribute__((ext_vector_type(2)));
typedef float f4 __attribute__((ext_vector_type(4)));

__device__ __forceinline__ float fast_sigmoid(float v) {
    return 1.0f / (1.0f + __expf(-v));
}
__device__ __forceinline__ float fast_tanh(float v) {
    // 1 - 2/(e^{2v}+1); stable at +-inf
    return 1.0f - 2.0f / (__expf(2.0f * v) + 1.0f);
}

__global__ __launch_bounds__(NTHR, 3) void lstm_seq_kernel(
    const float* __restrict__ x,      // [B, T, 1]
    const float* __restrict__ w_ih,   // [4H, 1]
    const float* __restrict__ w_hh,   // [4H, H]
    const float* __restrict__ b_ih,   // [4H]
    const float* __restrict__ b_hh,   // [4H]
    const float* __restrict__ w_out,  // [1, H]
    const float* __restrict__ b_out,  // [1]
    float* __restrict__ y)            // [B, T, 1]
{
    const int b    = blockIdx.x;
    const int tid  = threadIdx.x;
    const int half = (tid >= G_DIM) ? 1 : 0;   // wave-uniform (384 = 6-wave boundary)
    const int j    = tid - half * G_DIM;       // gate row 0..383

    __shared__ float h_s[2][H_DIM];   // double-buffered hidden state
    __shared__ float part_s[NTHR];    // raw dot partials (two halves)
    __shared__ float red_s[2];

    // 48 weights per thread as 24 f2 (VGPR pairs), pinned with asm barriers.
    f2 w2[24];
    {
        const f4* wrow = reinterpret_cast<const f4*>(w_hh + j * H_DIM + half * 48);
        #pragma unroll
        for (int q = 0; q < 12; ++q) {
            const f4 w = wrow[q];
            w2[2 * q + 0] = f2{w.x, w.y};
            w2[2 * q + 1] = f2{w.z, w.w};
        }
        #pragma unroll
        for (int q = 0; q < 24; ++q)
            asm volatile("" : "+v"(w2[q]));   // opaque: cannot be re-loaded/remat'd
    }

    // Cell-update params, only live on tid<96
    float bias4[4] = {0.f, 0.f, 0.f, 0.f};
    float wih4[4]  = {0.f, 0.f, 0.f, 0.f};
    float wout_j = 0.f;
    float c = 0.f;
    if (tid < H_DIM) {
        #pragma unroll
        for (int g = 0; g < 4; ++g) {
            bias4[g] = b_ih[g * H_DIM + tid] + b_hh[g * H_DIM + tid];
            wih4[g]  = w_ih[g * H_DIM + tid];
        }
        wout_j = w_out[tid];
        h_s[0][tid] = 0.f;
    }
    const float bout = b_out[0];
    __syncthreads();

    const float* xrow = x + (size_t)b * T_LEN;
    float*       yrow = y + (size_t)b * T_LEN;

    float x_next = 0.f;
    if (tid < H_DIM) x_next = xrow[0];

    for (int t = 0; t < T_LEN; ++t) {
        const float x_cur = x_next;
        if (tid < H_DIM && t + 1 < T_LEN) x_next = xrow[t + 1];

        const int p = t & 1;
        // 48-term dot: 12 broadcast ds_read_b128 + 24 v_pk_fma_f32 in 4 chains
        const f4* h4 = reinterpret_cast<const f4*>(&h_s[p][half * 48]);
        f2 acc[4] = {f2{0.f, 0.f}, f2{0.f, 0.f}, f2{0.f, 0.f}, f2{0.f, 0.f}};
        #pragma unroll
        for (int q = 0; q < 12; ++q) {
            const f4 hv = h4[q];
            const f2 hlo = f2{hv.x, hv.y};
            const f2 hhi = f2{hv.z, hv.w};
            asm("v_pk_fma_f32 %0, %1, %2, %0"
                : "+v"(acc[(2 * q + 0) & 3]) : "v"(hlo), "v"(w2[2 * q + 0]));
            asm("v_pk_fma_f32 %0, %1, %2, %0"
                : "+v"(acc[(2 * q + 1) & 3]) : "v"(hhi), "v"(w2[2 * q + 1]));
        }
        const f2 s01 = acc[0] + acc[1];
        const f2 s23 = acc[2] + acc[3];
        const f2 s   = s01 + s23;
        part_s[tid] = s.x + s.y;
        __syncthreads();  // bar A: partials ready; everyone done reading h_s[p]

        float partial = 0.f;
        if (tid < 128) {
            if (tid < H_DIM) {
                const float s0 = part_s[tid]             + part_s[G_DIM + tid]
                               + bias4[0] + x_cur * wih4[0];
                const float s1 = part_s[H_DIM + tid]     + part_s[G_DIM + H_DIM + tid]
                               + bias4[1] + x_cur * wih4[1];
                const float s2 = part_s[2 * H_DIM + tid] + part_s[G_DIM + 2 * H_DIM + tid]
                               + bias4[2] + x_cur * wih4[2];
                const float s3 = part_s[3 * H_DIM + tid] + part_s[G_DIM + 3 * H_DIM + tid]
                               + bias4[3] + x_cur * wih4[3];
                const float ig = fast_sigmoid(s0);
                const float fg = fast_sigmoid(s1);
                const float gg = fast_tanh(s2);
                const float og = fast_sigmoid(s3);
                c = fg * c + ig * gg;
                const float h = og * fast_tanh(c);
                h_s[p ^ 1][tid] = h;
                partial = h * wout_j;
            }
            // y_t reduction over waves 0,1 (tid 96..127 contribute 0)
            #pragma unroll
            for (int off = 32; off > 0; off >>= 1)
                partial += __shfl_down(partial, off, 64);
            if ((tid & 63) == 0) red_s[tid >> 6] = partial;
        }
        __syncthreads();  // bar B: h_s[p^1] + red_s ready

        if (tid == 0) yrow[t] = red_s[0] + red_s[1] + bout;  // overlaps next dot
    }
}

extern "C" void kernel_launch(void* const* d_in, const int* in_sizes, int n_in,
                              void* d_out, int out_size, void* d_ws, size_t ws_size,
                              hipStream_t stream) {
    const float* x     = (const float*)d_in[0];
    const float* w_ih  = (const float*)d_in[1];
    const float* w_hh  = (const float*)d_in[2];
    const float* b_ih  = (const float*)d_in[3];
    const float* b_hh  = (const float*)d_in[4];
    const float* w_out = (const float*)d_in[5];
    const float* b_out = (const float*)d_in[6];
    float* y = (float*)d_out;

    const int B = 128;
    lstm_seq_kernel<<<dim3(B), dim3(NTHR), 0, stream>>>(
        x, w_ih, w_hh, b_ih, b_hh, w_out, b_out, y);
}

// Round 4
// 5527.774 us; speedup vs baseline: 1.5086x; 1.3654x over previous
//
#include <hip/hip_runtime.h>

// SimpleLSTM B=128,T=8192,H=96. One block per batch, 384 threads (6 waves).
// R1-R3 post-mortem: all were DS-pipe-bound (~190 LDS instrs/step, ~2200 cyc)
// because every thread broadcast-read all 96 h values. Fix: the h-broadcast
// moves into the matrix pipe via mfma_f32_16x16x32_f16.
//   - W_hh rows PERMUTED: tile mt, quad q, regs 0..3 = gates i,f,g,o of cell
//     4mt+q  (perm row 16mt+4q+r <-> orig row r*96 + 4mt+q).
//   - 25th M-tile row 384 = w_out => y_t comes out of the MFMA for free.
//   - col-0 lanes ds_write_b128 their 4 accs to pre_s[4j..4j+4); threads j<96
//     do lane-packed activations + cell update (c in regs), write h (fp16,
//     double-buffered). 2 barriers/step, ~47 DS instrs/step vs ~190 before.
// fp16 only on W_hh/w_out/h (MFMA inputs); x, biases, gates, c, y in fp32.

#define T_LEN 8192
#define H_DIM 96
#define NTHR  384  // 6 waves

typedef float    f32x4 __attribute__((ext_vector_type(4)));
typedef _Float16 half8 __attribute__((ext_vector_type(8)));

__device__ __forceinline__ float fast_sigmoid(float v) {
    return 1.0f / (1.0f + __expf(-v));
}
__device__ __forceinline__ float fast_tanh(float v) {
    return 1.0f - 2.0f / (__expf(2.0f * v) + 1.0f);
}

__global__ __launch_bounds__(NTHR, 2) void lstm_mfma_kernel(
    const float* __restrict__ x,      // [B, T]
    const float* __restrict__ w_ih,   // [4H]
    const float* __restrict__ w_hh,   // [4H, H]
    const float* __restrict__ b_ih,   // [4H]
    const float* __restrict__ b_hh,   // [4H]
    const float* __restrict__ w_out,  // [H]
    const float* __restrict__ b_out,  // [1]
    float* __restrict__ y)            // [B, T]
{
    const int b    = blockIdx.x;
    const int tid  = threadIdx.x;
    const int wave = tid >> 6;
    const int lane = tid & 63;
    const int m    = lane & 15;   // A-operand row within tile / D col
    const int quad = lane >> 4;   // k-group

    __shared__ __align__(16) _Float16 h_s[2][H_DIM];  // double-buffered h (fp16)
    __shared__ __align__(16) float    pre_s[400];     // gate preacts (+y tile spill)

    // ---- A fragments: wave w owns tiles {4w..4w+3}, wave 5 also tile 24 (y).
    // A[m][k] layout: lane(m,quad) holds k = 32*kt + 8*quad + j, j=0..7.
    // perm row 16mt+m: cell quad qc=m>>2, gate r=m&3 -> orig row r*96+4mt+qc.
    const int ntile = (wave == 5) ? 5 : 4;
    f32x4 afr[5][3];
    #pragma unroll
    for (int s = 0; s < 5; ++s) {
        const int mt = (s < 4) ? (4 * wave + s) : 24;
        #pragma unroll
        for (int kt = 0; kt < 3; ++kt) {
            half8 f;
            if (s < ntile) {
                if (mt < 24) {
                    const int orig = (m & 3) * 96 + 4 * mt + (m >> 2);
                    const float* src = w_hh + orig * H_DIM + kt * 32 + quad * 8;
                    #pragma unroll
                    for (int jj = 0; jj < 8; ++jj) f[jj] = (_Float16)src[jj];
                } else {  // y tile: row 0 = w_out, rows 1..15 = 0
                    #pragma unroll
                    for (int jj = 0; jj < 8; ++jj)
                        f[jj] = (m == 0) ? (_Float16)w_out[kt * 32 + quad * 8 + jj]
                                         : (_Float16)0.0f;
                }
            } else {
                #pragma unroll
                for (int jj = 0; jj < 8; ++jj) f[jj] = (_Float16)0.0f;
            }
            afr[s][kt] = __builtin_bit_cast(f32x4, f);
            asm volatile("" : "+v"(afr[s][kt]));  // pin in VGPRs (no remat/sink)
        }
    }

    // ---- cell-update params (threads 0..95 own cell j = tid)
    float bias4[4] = {0.f, 0.f, 0.f, 0.f};
    float wih4[4]  = {0.f, 0.f, 0.f, 0.f};
    float c = 0.f;
    if (tid < H_DIM) {
        #pragma unroll
        for (int g = 0; g < 4; ++g) {
            bias4[g] = b_ih[g * H_DIM + tid] + b_hh[g * H_DIM + tid];
            wih4[g]  = w_ih[g * H_DIM + tid];
        }
        h_s[0][tid] = (_Float16)0.0f;
    }
    const float bout = b_out[0];
    __syncthreads();

    const float* xrow = x + (size_t)b * T_LEN;
    float*       yrow = y + (size_t)b * T_LEN;
    float x_next = (tid < H_DIM) ? xrow[0] : 0.f;

    // iter it: B-frags read h_{it-1} (h_s[it&1]); cell phase makes h_it;
    // y tile yields y_{it-1}. Extra iter it==T_LEN flushes y[T-1].
    for (int it = 0; it <= T_LEN; ++it) {
        const int p = it & 1;
        const float x_cur = x_next;
        if (tid < H_DIM && it + 1 < T_LEN) x_next = xrow[it + 1];

        // B fragments: lane needs h[32*kt + 8*quad + j] (col index irrelevant)
        f32x4 bfr[3];
        #pragma unroll
        for (int kt = 0; kt < 3; ++kt)
            bfr[kt] = *reinterpret_cast<const f32x4*>(&h_s[p][kt * 32 + quad * 8]);

        f32x4 acc4;  // y-tile acc (wave 5)
        #pragma unroll
        for (int s = 0; s < 5; ++s) {
            if (s < ntile) {
                f32x4 a = {0.f, 0.f, 0.f, 0.f};
                #pragma unroll
                for (int kt = 0; kt < 3; ++kt)
                    a = __builtin_amdgcn_mfma_f32_16x16x32_f16(
                            __builtin_bit_cast(half8, afr[s][kt]),
                            __builtin_bit_cast(half8, bfr[kt]), a, 0, 0, 0);
                const int mt = (s < 4) ? (4 * wave + s) : 24;
                // D: col = lane&15, row = quad*4 + reg. Col-0 lanes stash 4 rows.
                if (m == 0)
                    *reinterpret_cast<f32x4*>(&pre_s[16 * mt + 4 * quad]) = a;
                if (s == 4) acc4 = a;
            }
        }
        if (wave == 5 && lane == 0 && it > 0)
            yrow[it - 1] = acc4.x + bout;  // row 384 = w_out . h_{it-1}

        __syncthreads();  // pre_s ready

        if (it < T_LEN && tid < H_DIM) {
            const f32x4 pre4 = *reinterpret_cast<const f32x4*>(&pre_s[4 * tid]);
            const float s0 = pre4.x + bias4[0] + x_cur * wih4[0];
            const float s1 = pre4.y + bias4[1] + x_cur * wih4[1];
            const float s2 = pre4.z + bias4[2] + x_cur * wih4[2];
            const float s3 = pre4.w + bias4[3] + x_cur * wih4[3];
            const float ig = fast_sigmoid(s0);
            const float fg = fast_sigmoid(s1);
            const float gg = fast_tanh(s2);
            const float og = fast_sigmoid(s3);
            c = fg * c + ig * gg;
            const float h = og * fast_tanh(c);
            h_s[p ^ 1][tid] = (_Float16)h;
        }
        __syncthreads();  // h_s[p^1] ready for next iter's B-frag reads
    }
}

extern "C" void kernel_launch(void* const* d_in, const int* in_sizes, int n_in,
                              void* d_out, int out_size, void* d_ws, size_t ws_size,
                              hipStream_t stream) {
    const float* x     = (const float*)d_in[0];
    const float* w_ih  = (const float*)d_in[1];
    const float* w_hh  = (const float*)d_in[2];
    const float* b_ih  = (const float*)d_in[3];
    const float* b_hh  = (const float*)d_in[4];
    const float* w_out = (const float*)d_in[5];
    const float* b_out = (const float*)d_in[6];
    float* y = (float*)d_out;

    const int B = 128;
    lstm_mfma_kernel<<<dim3(B), dim3(NTHR), 0, stream>>>(
        x, w_ih, w_hh, b_ih, b_hh, w_out, b_out, y);
}